// Round 8
// baseline (483.208 us; speedup 1.0000x reference)
//
#include <hip/hip_runtime.h>
#include <hip/hip_bf16.h>

#define BATCH 64
#define SEQ   256
#define EMB   64
#define QKVD  64
#define KD    8192      // L*EMB
#define ND    8192      // L*QKV
#define SEQD  16384     // SEQ*EMB (per-batch x row)
#define BKT   256       // k extent per tile (1KB of fp32 per W row)
#define NTK   (KD / BKT)   // 32 k-tiles

typedef __attribute__((ext_vector_type(8))) short bf16x8;
typedef __attribute__((ext_vector_type(4))) float f32x4;

struct WArgs { const float* W[6]; const float* b[6]; };

// branchless round-to-nearest-even fp32 -> bf16 bits (inputs are finite)
__device__ __forceinline__ short f2bf(float f) {
    unsigned u = __builtin_bit_cast(unsigned, f);
    u += 0x7fffu + ((u >> 16) & 1u);
    return (short)(u >> 16);
}

// async global->LDS, 16B per lane; LDS dest = wave-uniform base + lane*16
__device__ __forceinline__ void gl16(const void* g, void* l) {
    __builtin_amdgcn_global_load_lds(
        (const __attribute__((address_space(1))) void*)g,
        (__attribute__((address_space(3))) void*)l, 16, 0, 0);
}

// ---------------- kernel 1: x fp32 -> bf16 ----------------------------------
__global__ __launch_bounds__(256)
void cvt_x_kernel(const float* __restrict__ x, short* __restrict__ xb) {
    const int i = (blockIdx.x * 256 + threadIdx.x) * 4;
    float4 v = *reinterpret_cast<const float4*>(x + i);
    short4 o;
    o.x = f2bf(v.x); o.y = f2bf(v.y); o.z = f2bf(v.z); o.w = f2bf(v.w);
    *reinterpret_cast<short4*>(xb + i) = o;
}

// ---------------- kernel 2: QKV projections ---------------------------------
// C[m][n] = sum_k xs[m,k] * W[n,k] + b[n], per gi in [0,6)
// 1 block/CU (128KB LDS), 4 waves, ZERO barriers. Each wave owns 16 W rows,
// wave-private ring-2 LDS slots [16][256]f32. Every gl_lds issue = one FULL
// 1KB contiguous row-chunk (copy-shaped instruction footprint -> DRAM page
// efficiency). A (L2-resident) loaded direct-to-VGPR per tile in one batch.
// Persistent: each block processes 3 consecutive n-tiles (6MB sequential W).
__global__ __launch_bounds__(256, 1)
void qkv_gemm_kernel(const short* __restrict__ xb, WArgs wa,
                     float* __restrict__ qkv) {
    __shared__ __attribute__((aligned(16))) float W_lds[4][2][16 * BKT]; // 128KB

    const int wv = threadIdx.x >> 6;
    const int ln = threadIdx.x & 63;
    const int r  = ln & 15;           // n within wave tile / A row in frag
    const int kb = ln >> 4;           // k sub-block of 8 within 32

    float* const Wl0 = &W_lds[wv][0][0];
    float* const Wl1 = &W_lds[wv][1][0];

    for (int nt = 0; nt < 3; ++nt) {
        const int logical = blockIdx.x * 3 + nt;
        const int gi = logical >> 7;               // 0..5
        const int n0 = (logical & 127) * 64;       // n-tile origin
        const int g  = gi / 3;

        const char*  __restrict__ Wbase =
            (const char*)(wa.W[gi] + (size_t)(n0 + wv * 16) * KD);
        const short* __restrict__ Ag = xb + g * KD;

        f32x4 acc0 = {0.f, 0.f, 0.f, 0.f};
        f32x4 acc1 = acc0, acc2 = acc0, acc3 = acc0;

        auto stage = [&](int t, float* slot) {
            const char* tb = Wbase + (size_t)t * (BKT * 4);
            #pragma unroll
            for (int row = 0; row < 16; ++row) {   // 1 issue = 1KB contiguous
                gl16(tb + (size_t)row * (KD * 4) + ((ln ^ (row & 7)) << 4),
                     (char*)slot + row * 1024);
            }
        };

        stage(0, Wl0);
        stage(1, Wl1);

        for (int t = 0; t < NTK; ++t) {
            float* slot = (t & 1) ? Wl1 : Wl0;

            // A fragments for this tile: 32 straight-line loads (L2)
            bf16x8 afr[32];
            {
                const short* Ab = Ag + t * BKT + kb * 8;
                #pragma unroll
                for (int s = 0; s < 8; ++s)
                    #pragma unroll
                    for (int mi = 0; mi < 4; ++mi)
                        afr[s * 4 + mi] = *(const bf16x8*)
                            (Ab + (size_t)(mi * 16 + r) * SEQD + s * 32);
            }

            asm volatile("s_waitcnt vmcnt(0)" ::: "memory");
            __builtin_amdgcn_sched_barrier(0);

            const float* wrow = slot + r * BKT;
            const int key = r & 7;
            #pragma unroll
            for (int s = 0; s < 8; ++s) {
                const int c0 = s * 8 + kb * 2;
                f32x4 w0 = *(const f32x4*)(wrow + (((c0)     ^ key) * 4));
                f32x4 w1 = *(const f32x4*)(wrow + (((c0 + 1) ^ key) * 4));
                bf16x8 bb;
                bb[0] = f2bf(w0[0]); bb[1] = f2bf(w0[1]);
                bb[2] = f2bf(w0[2]); bb[3] = f2bf(w0[3]);
                bb[4] = f2bf(w1[0]); bb[5] = f2bf(w1[1]);
                bb[6] = f2bf(w1[2]); bb[7] = f2bf(w1[3]);
                acc0 = __builtin_amdgcn_mfma_f32_16x16x32_bf16(afr[s*4+0], bb, acc0, 0, 0, 0);
                acc1 = __builtin_amdgcn_mfma_f32_16x16x32_bf16(afr[s*4+1], bb, acc1, 0, 0, 0);
                acc2 = __builtin_amdgcn_mfma_f32_16x16x32_bf16(afr[s*4+2], bb, acc2, 0, 0, 0);
                acc3 = __builtin_amdgcn_mfma_f32_16x16x32_bf16(afr[s*4+3], bb, acc3, 0, 0, 0);
            }

            asm volatile("s_waitcnt lgkmcnt(0)" ::: "memory");
            __builtin_amdgcn_sched_barrier(0);
            if (t + 2 < NTK) stage(t + 2, slot);   // wave-private WAR safe
        }

        // D layout (m89): col = lane&15, row = (lane>>4)*4 + reg
        const int nbr = n0 + wv * 16 + r;
        const float bias = wa.b[gi][nbr];
        float* orow = qkv + (size_t)gi * (BATCH * ND) + nbr;
        #pragma unroll
        for (int reg = 0; reg < 4; ++reg) {
            const int m = kb * 4 + reg;
            orow[(size_t)(m)      * ND] = acc0[reg] + bias;
            orow[(size_t)(m + 16) * ND] = acc1[reg] + bias;
            orow[(size_t)(m + 32) * ND] = acc2[reg] + bias;
            orow[(size_t)(m + 48) * ND] = acc3[reg] + bias;
        }
    }
}

// ---------------- kernel 3: attention per (batch, group) -------------------
// scores[i][j] = Q[i,:]·K[j,:]; softmax over i (query axis); Z = attn·V; ×0.125
__global__ __launch_bounds__(256)
void attn_kernel(const float* __restrict__ qkv, float* __restrict__ out) {
    __shared__ float Ql[128 * 65];   // Q, then reused for V
    __shared__ float Kl[128 * 65];
    __shared__ float Sc[128 * 129];
    __shared__ float Pm[256];
    __shared__ float Ps[256];
    __shared__ float Rden[128];

    const int b = blockIdx.x;
    const int g = blockIdx.y;
    const int t = threadIdx.x;

    const float* __restrict__ Qg = qkv + ((size_t)(3 * g + 0) * BATCH + b) * ND;
    const float* __restrict__ Kg = qkv + ((size_t)(3 * g + 1) * BATCH + b) * ND;
    const float* __restrict__ Vg = qkv + ((size_t)(3 * g + 2) * BATCH + b) * ND;

    for (int e = t; e < 8192; e += 256) {
        const int i = e >> 6, k = e & 63;
        Ql[i * 65 + k] = Qg[e];
        Kl[i * 65 + k] = Kg[e];
    }
    __syncthreads();

    // scores: 8x8 register tile per thread
    {
        const int i0 = (t >> 4) * 8;
        const int j0 = (t & 15) * 8;
        float s[8][8];
        #pragma unroll
        for (int rr = 0; rr < 8; ++rr)
            #pragma unroll
            for (int cc = 0; cc < 8; ++cc) s[rr][cc] = 0.f;
        for (int k = 0; k < 64; ++k) {
            float qv[8], kv[8];
            #pragma unroll
            for (int rr = 0; rr < 8; ++rr) qv[rr] = Ql[(i0 + rr) * 65 + k];
            #pragma unroll
            for (int cc = 0; cc < 8; ++cc) kv[cc] = Kl[(j0 + cc) * 65 + k];
            #pragma unroll
            for (int rr = 0; rr < 8; ++rr)
                #pragma unroll
                for (int cc = 0; cc < 8; ++cc)
                    s[rr][cc] = fmaf(qv[rr], kv[cc], s[rr][cc]);
        }
        #pragma unroll
        for (int rr = 0; rr < 8; ++rr)
            #pragma unroll
            for (int cc = 0; cc < 8; ++cc)
                Sc[(i0 + rr) * 129 + (j0 + cc)] = s[rr][cc];
    }
    __syncthreads();

    // V fill (Q dead) + per-column partial max; column j, half h
    const int j = t & 127, h = t >> 7;
    {
        for (int e = t; e < 8192; e += 256) {
            const int i = e >> 6, k = e & 63;
            Ql[i * 65 + k] = Vg[e];
        }
        float m = -3.0e38f;
        for (int i = h * 64; i < h * 64 + 64; ++i)
            m = fmaxf(m, Sc[i * 129 + j]);
        Pm[h * 128 + j] = m;
    }
    __syncthreads();
    {
        const float m = fmaxf(Pm[j], Pm[128 + j]);
        float sum = 0.f;
        for (int i = h * 64; i < h * 64 + 64; ++i) {
            const float e = __expf(Sc[i * 129 + j] - m);
            Sc[i * 129 + j] = e;
            sum += e;
        }
        Ps[h * 128 + j] = sum;
    }
    __syncthreads();
    if (t < 128) Rden[t] = 1.0f / (Ps[t] + Ps[128 + t]);
    __syncthreads();

    // PV: 8 rows x 4 cols per thread
    {
        const int i0 = (t >> 4) * 8;
        const int k0 = (t & 15) * 4;
        float z[8][4];
        #pragma unroll
        for (int rr = 0; rr < 8; ++rr)
            #pragma unroll
            for (int cc = 0; cc < 4; ++cc) z[rr][cc] = 0.f;
        for (int jj = 0; jj < 128; ++jj) {
            const float rd = Rden[jj];
            float av[8], vv[4];
            #pragma unroll
            for (int rr = 0; rr < 8; ++rr) av[rr] = Sc[(i0 + rr) * 129 + jj] * rd;
            #pragma unroll
            for (int cc = 0; cc < 4; ++cc) vv[cc] = Ql[jj * 65 + k0 + cc];
            #pragma unroll
            for (int rr = 0; rr < 8; ++rr)
                #pragma unroll
                for (int cc = 0; cc < 4; ++cc)
                    z[rr][cc] = fmaf(av[rr], vv[cc], z[rr][cc]);
        }
        float* op = out + (size_t)b * (SEQ * QKVD) + (size_t)(g * 128) * QKVD + k0;
        #pragma unroll
        for (int rr = 0; rr < 8; ++rr) {
            float4 o;
            o.x = z[rr][0] * 0.125f; o.y = z[rr][1] * 0.125f;
            o.z = z[rr][2] * 0.125f; o.w = z[rr][3] * 0.125f;
            *reinterpret_cast<float4*>(op + (size_t)(i0 + rr) * QKVD) = o;
        }
    }
}

// ---------------- launcher --------------------------------------------------
extern "C" void kernel_launch(void* const* d_in, const int* in_sizes, int n_in,
                              void* d_out, int out_size, void* d_ws, size_t ws_size,
                              hipStream_t stream) {
    const float* x = (const float*)d_in[0];
    WArgs wa;
    for (int g = 0; g < 2; ++g)
        for (int q = 0; q < 3; ++q) {
            wa.W[g * 3 + q] = (const float*)d_in[1 + g * 6 + q * 2];
            wa.b[g * 3 + q] = (const float*)d_in[2 + g * 6 + q * 2];
        }

    short* xb  = (short*)d_ws;                                      // 2 MiB
    float* qkv = (float*)((char*)d_ws + (size_t)4 * 1024 * 1024);   // 12.6 MiB

    cvt_x_kernel<<<dim3(1024), dim3(256), 0, stream>>>(x, xb);
    qkv_gemm_kernel<<<dim3(256), dim3(256), 0, stream>>>(xb, wa, qkv);
    attn_kernel<<<dim3(BATCH, 2), dim3(256), 0, stream>>>(qkv, (float*)d_out);
}

// Round 9
// 344.962 us; speedup vs baseline: 1.4008x; 1.4008x over previous
//
#include <hip/hip_runtime.h>
#include <hip/hip_bf16.h>

#define BATCH 64
#define SEQ   256
#define EMB   64
#define QKVD  64
#define KD    8192      // L*EMB
#define ND    8192      // L*QKV
#define SEQD  16384     // SEQ*EMB (per-batch x row)
#define BKT   256       // k per tile: W row chunk = 1KB contiguous
#define NTK   (KD / BKT)   // 32 k-tiles

typedef __attribute__((ext_vector_type(8))) short bf16x8;
typedef __attribute__((ext_vector_type(4))) float f32x4;

struct WArgs { const float* W[6]; const float* b[6]; };

// branchless round-to-nearest-even fp32 -> bf16 bits (inputs are finite)
__device__ __forceinline__ short f2bf(float f) {
    unsigned u = __builtin_bit_cast(unsigned, f);
    u += 0x7fffu + ((u >> 16) & 1u);
    return (short)(u >> 16);
}

// async global->LDS, 16B per lane; LDS dest = wave-uniform base + lane*16
__device__ __forceinline__ void gl16(const void* g, void* l) {
    __builtin_amdgcn_global_load_lds(
        (const __attribute__((address_space(1))) void*)g,
        (__attribute__((address_space(3))) void*)l, 16, 0, 0);
}

__device__ __forceinline__ void barrier_fenced() {
    asm volatile("" ::: "memory");
    __builtin_amdgcn_s_barrier();
    asm volatile("" ::: "memory");
}

// ---------------- kernel 1: x fp32 -> bf16 ----------------------------------
__global__ __launch_bounds__(256)
void cvt_x_kernel(const float* __restrict__ x, short* __restrict__ xb) {
    const int i = (blockIdx.x * 256 + threadIdx.x) * 4;
    float4 v = *reinterpret_cast<const float4*>(x + i);
    short4 o;
    o.x = f2bf(v.x); o.y = f2bf(v.y); o.z = f2bf(v.z); o.w = f2bf(v.w);
    *reinterpret_cast<short4*>(xb + i) = o;
}

// ---------------- kernel 2: QKV projections ---------------------------------
// C[m][n] = sum_k xs[m,k] * W[n,k] + b[n], per gi in [0,6)
// 1 block/CU (160KB LDS), 4 waves, persistent over 3 n-tiles (6MB sequential W
// stream per block). BK=256: every W gl_lds issue = 1KB contiguous (DRAM
// row-buffer efficient). W double-buffered (2x64KB), A single-buffered (32KB).
// Counted vmcnt(16): W(t+1)'s 64KB stays in flight across compute(t).
__global__ __launch_bounds__(256, 1)
void qkv_gemm_kernel(const short* __restrict__ xb, WArgs wa,
                     float* __restrict__ qkv) {
    __shared__ __attribute__((aligned(16))) float W_lds[2][64 * BKT]; // 128KB
    __shared__ __attribute__((aligned(16))) short A_lds[64 * BKT];    // 32KB

    const int wv = threadIdx.x >> 6;
    const int ln = threadIdx.x & 63;
    const int r  = ln & 15;           // n within wave tile / A row in frag
    const int kb = ln >> 4;           // k sub-block of 8 within 32
    const int key = r & 7;

    for (int nt = 0; nt < 3; ++nt) {
        const int logical = blockIdx.x * 3 + nt;
        const int gi = logical >> 7;               // 0..5
        const int n0 = (logical & 127) * 64;       // n-tile origin
        const int g  = gi / 3;

        const char*  __restrict__ Wb8 =
            (const char*)(wa.W[gi] + (size_t)(n0 + wv * 16) * KD);
        const short* __restrict__ Ag = xb + g * KD;

        f32x4 acc0 = {0.f, 0.f, 0.f, 0.f};
        f32x4 acc1 = acc0, acc2 = acc0, acc3 = acc0;

        auto stageW = [&](int t, int slot) {       // 16 issues = 16KB/wave
            const char* tb = Wb8 + (size_t)t * 1024;
            #pragma unroll
            for (int i = 0; i < 16; ++i) {         // 1 issue = 1KB contiguous
                gl16(tb + (size_t)i * (KD * 4) + ((ln ^ (i & 7)) << 4),
                     (char*)&W_lds[slot][0] + (wv * 16 + i) * 1024);
            }
        };
        auto stageA = [&](int t) {                 // 8 issues/wave, coop 64 rows
            #pragma unroll
            for (int j = 0; j < 8; ++j) {
                const int jj  = wv * 8 + j;        // issue covers rows 2jj,2jj+1
                const int row = 2 * jj + (ln >> 5);
                const int c   = (ln & 31) ^ (row & 7);
                gl16((const char*)(Ag + (size_t)row * SEQD) + (size_t)t * 512 + (c << 4),
                     (char*)&A_lds[0] + jj * 1024);
            }
        };

        auto compute = [&](int slot) {
            const float* Wrow = &W_lds[slot][0] + (wv * 16 + r) * BKT;
            const char*  Ab   = (const char*)&A_lds[0];
            #pragma unroll
            for (int s = 0; s < 8; ++s) {
                const int cg = s * 8 + kb * 2;
                f32x4 w0 = *(const f32x4*)(Wrow + (((cg)     ^ key) << 2));
                f32x4 w1 = *(const f32x4*)(Wrow + (((cg + 1) ^ key) << 2));
                bf16x8 bb;
                bb[0] = f2bf(w0[0]); bb[1] = f2bf(w0[1]);
                bb[2] = f2bf(w0[2]); bb[3] = f2bf(w0[3]);
                bb[4] = f2bf(w1[0]); bb[5] = f2bf(w1[1]);
                bb[6] = f2bf(w1[2]); bb[7] = f2bf(w1[3]);
                const int ca = (s * 4 + kb) ^ key;  // A 16B-chunk (swizzled)
                const bf16x8 a0 = *(const bf16x8*)(Ab + (r)      * 512 + (ca << 4));
                const bf16x8 a1 = *(const bf16x8*)(Ab + (r + 16) * 512 + (ca << 4));
                const bf16x8 a2 = *(const bf16x8*)(Ab + (r + 32) * 512 + (ca << 4));
                const bf16x8 a3 = *(const bf16x8*)(Ab + (r + 48) * 512 + (ca << 4));
                acc0 = __builtin_amdgcn_mfma_f32_16x16x32_bf16(a0, bb, acc0, 0, 0, 0);
                acc1 = __builtin_amdgcn_mfma_f32_16x16x32_bf16(a1, bb, acc1, 0, 0, 0);
                acc2 = __builtin_amdgcn_mfma_f32_16x16x32_bf16(a2, bb, acc2, 0, 0, 0);
                acc3 = __builtin_amdgcn_mfma_f32_16x16x32_bf16(a3, bb, acc3, 0, 0, 0);
            }
        };

        // prologue ledger order: W(0), A(0), W(1) -> vmcnt(16) at t=0 is exact
        stageW(0, 0);
        stageA(0);
        stageW(1, 1);

        for (int t = 0; t < NTK; ++t) {
            if (t < NTK - 2) { asm volatile("s_waitcnt vmcnt(16)" ::: "memory"); }
            else             { asm volatile("s_waitcnt vmcnt(0)"  ::: "memory"); }
            __builtin_amdgcn_sched_barrier(0);
            barrier_fenced();            // all waves' tile-t stages in LDS
            compute(t & 1);
            barrier_fenced();            // WAR: A buf + W slot free
            if (t + 1 < NTK) stageA(t + 1);
            if (t + 2 < NTK) stageW(t + 2, t & 1);
        }
        barrier_fenced();

        // D layout (m89): col = lane&15, row = (lane>>4)*4 + reg
        const int nbr = n0 + wv * 16 + r;
        const float bias = wa.b[gi][nbr];
        float* orow = qkv + (size_t)gi * (BATCH * ND) + nbr;
        #pragma unroll
        for (int reg = 0; reg < 4; ++reg) {
            const int m = kb * 4 + reg;
            orow[(size_t)(m)      * ND] = acc0[reg] + bias;
            orow[(size_t)(m + 16) * ND] = acc1[reg] + bias;
            orow[(size_t)(m + 32) * ND] = acc2[reg] + bias;
            orow[(size_t)(m + 48) * ND] = acc3[reg] + bias;
        }
    }
}

// ---------------- kernel 3: attention per (batch, group) -------------------
// scores[i][j] = Q[i,:]·K[j,:]; softmax over i (query axis); Z = attn·V; ×0.125
__global__ __launch_bounds__(256)
void attn_kernel(const float* __restrict__ qkv, float* __restrict__ out) {
    __shared__ float Ql[128 * 65];   // Q, then reused for V
    __shared__ float Kl[128 * 65];
    __shared__ float Sc[128 * 129];
    __shared__ float Pm[256];
    __shared__ float Ps[256];
    __shared__ float Rden[128];

    const int b = blockIdx.x;
    const int g = blockIdx.y;
    const int t = threadIdx.x;

    const float* __restrict__ Qg = qkv + ((size_t)(3 * g + 0) * BATCH + b) * ND;
    const float* __restrict__ Kg = qkv + ((size_t)(3 * g + 1) * BATCH + b) * ND;
    const float* __restrict__ Vg = qkv + ((size_t)(3 * g + 2) * BATCH + b) * ND;

    for (int e = t; e < 8192; e += 256) {
        const int i = e >> 6, k = e & 63;
        Ql[i * 65 + k] = Qg[e];
        Kl[i * 65 + k] = Kg[e];
    }
    __syncthreads();

    // scores: 8x8 register tile per thread
    {
        const int i0 = (t >> 4) * 8;
        const int j0 = (t & 15) * 8;
        float s[8][8];
        #pragma unroll
        for (int rr = 0; rr < 8; ++rr)
            #pragma unroll
            for (int cc = 0; cc < 8; ++cc) s[rr][cc] = 0.f;
        for (int k = 0; k < 64; ++k) {
            float qv[8], kv[8];
            #pragma unroll
            for (int rr = 0; rr < 8; ++rr) qv[rr] = Ql[(i0 + rr) * 65 + k];
            #pragma unroll
            for (int cc = 0; cc < 8; ++cc) kv[cc] = Kl[(j0 + cc) * 65 + k];
            #pragma unroll
            for (int rr = 0; rr < 8; ++rr)
                #pragma unroll
                for (int cc = 0; cc < 8; ++cc)
                    s[rr][cc] = fmaf(qv[rr], kv[cc], s[rr][cc]);
        }
        #pragma unroll
        for (int rr = 0; rr < 8; ++rr)
            #pragma unroll
            for (int cc = 0; cc < 8; ++cc)
                Sc[(i0 + rr) * 129 + (j0 + cc)] = s[rr][cc];
    }
    __syncthreads();

    // V fill (Q dead) + per-column partial max; column j, half h
    const int j = t & 127, h = t >> 7;
    {
        for (int e = t; e < 8192; e += 256) {
            const int i = e >> 6, k = e & 63;
            Ql[i * 65 + k] = Vg[e];
        }
        float m = -3.0e38f;
        for (int i = h * 64; i < h * 64 + 64; ++i)
            m = fmaxf(m, Sc[i * 129 + j]);
        Pm[h * 128 + j] = m;
    }
    __syncthreads();
    {
        const float m = fmaxf(Pm[j], Pm[128 + j]);
        float sum = 0.f;
        for (int i = h * 64; i < h * 64 + 64; ++i) {
            const float e = __expf(Sc[i * 129 + j] - m);
            Sc[i * 129 + j] = e;
            sum += e;
        }
        Ps[h * 128 + j] = sum;
    }
    __syncthreads();
    if (t < 128) Rden[t] = 1.0f / (Ps[t] + Ps[128 + t]);
    __syncthreads();

    // PV: 8 rows x 4 cols per thread
    {
        const int i0 = (t >> 4) * 8;
        const int k0 = (t & 15) * 4;
        float z[8][4];
        #pragma unroll
        for (int rr = 0; rr < 8; ++rr)
            #pragma unroll
            for (int cc = 0; cc < 4; ++cc) z[rr][cc] = 0.f;
        for (int jj = 0; jj < 128; ++jj) {
            const float rd = Rden[jj];
            float av[8], vv[4];
            #pragma unroll
            for (int rr = 0; rr < 8; ++rr) av[rr] = Sc[(i0 + rr) * 129 + jj] * rd;
            #pragma unroll
            for (int cc = 0; cc < 4; ++cc) vv[cc] = Ql[jj * 65 + k0 + cc];
            #pragma unroll
            for (int rr = 0; rr < 8; ++rr)
                #pragma unroll
                for (int cc = 0; cc < 4; ++cc)
                    z[rr][cc] = fmaf(av[rr], vv[cc], z[rr][cc]);
        }
        float* op = out + (size_t)b * (SEQ * QKVD) + (size_t)(g * 128) * QKVD + k0;
        #pragma unroll
        for (int rr = 0; rr < 8; ++rr) {
            float4 o;
            o.x = z[rr][0] * 0.125f; o.y = z[rr][1] * 0.125f;
            o.z = z[rr][2] * 0.125f; o.w = z[rr][3] * 0.125f;
            *reinterpret_cast<float4*>(op + (size_t)(i0 + rr) * QKVD) = o;
        }
    }
}

// ---------------- launcher --------------------------------------------------
extern "C" void kernel_launch(void* const* d_in, const int* in_sizes, int n_in,
                              void* d_out, int out_size, void* d_ws, size_t ws_size,
                              hipStream_t stream) {
    const float* x = (const float*)d_in[0];
    WArgs wa;
    for (int g = 0; g < 2; ++g)
        for (int q = 0; q < 3; ++q) {
            wa.W[g * 3 + q] = (const float*)d_in[1 + g * 6 + q * 2];
            wa.b[g * 3 + q] = (const float*)d_in[2 + g * 6 + q * 2];
        }

    short* xb  = (short*)d_ws;                                      // 2 MiB
    float* qkv = (float*)((char*)d_ws + (size_t)4 * 1024 * 1024);   // 12.6 MiB

    cvt_x_kernel<<<dim3(1024), dim3(256), 0, stream>>>(x, xb);
    qkv_gemm_kernel<<<dim3(256), dim3(256), 0, stream>>>(xb, wa, qkv);
    attn_kernel<<<dim3(BATCH, 2), dim3(256), 0, stream>>>(qkv, (float*)d_out);
}